// Round 5
// baseline (1478.526 us; speedup 1.0000x reference)
//
#include <hip/hip_runtime.h>
#include <math.h>

constexpr int N_EDGES = 800000;
constexpr int D_IN    = 40;   // 8 feat + 16 from + 16 to
constexpr int H       = 64;
constexpr int D_OUT   = 16;
constexpr int EB      = 128;  // edges per block (800000 % 128 == 0)

// 256 threads = 4 waves. Wave w owns output chunk [16w,16w+16) (L1/L2) and
// [4w,4w+4) (L3). Lane l owns edges {2l, 2l+1}. Weights/bias stream through
// the scalar path (s_load, wave-uniform address via readfirstlane); activations
// through LDS as contiguous ds_read_b64 (bandwidth-floor, conflict-free).
__global__ __launch_bounds__(256, 2) void edge_mlp_v3(
    const float* __restrict__ coords,
    const float* __restrict__ feat,
    const float* __restrict__ mask,
    const int*   __restrict__ a_from,
    const int*   __restrict__ a_to,
    const float* __restrict__ fW0, const float* __restrict__ fb0,
    const float* __restrict__ fW1, const float* __restrict__ fb1,
    const float* __restrict__ fW2, const float* __restrict__ fb2,
    const float* __restrict__ tW0, const float* __restrict__ tb0,
    const float* __restrict__ tW1, const float* __restrict__ tb1,
    const float* __restrict__ tW2, const float* __restrict__ tb2,
    float* __restrict__ acc_out)
{
    __shared__ float Xs[D_IN * EB];   // X^T: Xs[k][e], masked input
    __shared__ float Hs[H * EB];      // H^T
    __shared__ float ms[EB];
    __shared__ int   nodes[2][EB];

    const int tid  = threadIdx.x;
    const int lane = tid & 63;
    const int uwid = __builtin_amdgcn_readfirstlane(tid >> 6);  // 0..3, SGPR
    const int e0   = blockIdx.x * EB;

    // ---------------- staging ----------------
    if (tid < EB) {
        ms[tid]       = mask[e0 + tid];
        nodes[0][tid] = a_from[e0 + tid];
        nodes[1][tid] = a_to[e0 + tid];
    }
    {   // feat -> rows 0..7 ; thread = (edge, half)
        const int e = tid >> 1, half = tid & 1;
        const float m = mask[e0 + e];
        float4 v = reinterpret_cast<const float4*>(feat)[(size_t)(e0 + e) * 2 + half];
        const int r = half * 4;
        Xs[(r + 0) * EB + e] = v.x * m;
        Xs[(r + 1) * EB + e] = v.y * m;
        Xs[(r + 2) * EB + e] = v.z * m;
        Xs[(r + 3) * EB + e] = v.w * m;
    }
    {   // coords -> rows 8..23 (from), 24..39 (to) ; thread = (edge, which)
        const int e = tid >> 1, which = tid & 1;
        const float m = mask[e0 + e];
        const int n = which ? a_to[e0 + e] : a_from[e0 + e];
        const float4* c4 = reinterpret_cast<const float4*>(coords + (size_t)n * 16);
        const int rbase = 8 + which * 16;
        #pragma unroll
        for (int q = 0; q < 4; ++q) {
            float4 v = c4[q];
            Xs[(rbase + 4*q + 0) * EB + e] = v.x * m;
            Xs[(rbase + 4*q + 1) * EB + e] = v.y * m;
            Xs[(rbase + 4*q + 2) * EB + e] = v.z * m;
            Xs[(rbase + 4*q + 3) * EB + e] = v.w * m;
        }
    }
    __syncthreads();

    auto run_mlp = [&](const float* __restrict__ W0, const float* __restrict__ b0,
                       const float* __restrict__ W1, const float* __restrict__ b1,
                       const float* __restrict__ W2, const float* __restrict__ b2,
                       const int which)
    {
        // ---- layer 1: 40 -> 64, ReLU. acc[edge][j], j in wave's 16-chunk.
        float h0[2][16];
        {
            const float* __restrict__ bb = b0 + uwid * 16;
            #pragma unroll
            for (int j = 0; j < 16; ++j) { const float b = bb[j]; h0[0][j] = b; h0[1][j] = b; }
            const float* __restrict__ wb = W0 + uwid * 16;
            #pragma unroll
            for (int k = 0; k < D_IN; ++k) {
                const float2 xv = *reinterpret_cast<const float2*>(&Xs[k * EB + 2 * lane]);
                const float* __restrict__ w = wb + k * H;
                #pragma unroll
                for (int j = 0; j < 16; ++j) {
                    h0[0][j] = fmaf(xv.x, w[j], h0[0][j]);
                    h0[1][j] = fmaf(xv.y, w[j], h0[1][j]);
                }
            }
            #pragma unroll
            for (int i = 0; i < 2; ++i)
                #pragma unroll
                for (int j = 0; j < 16; ++j) h0[i][j] = fmaxf(h0[i][j], 0.0f);
        }

        // prior readers of Hs (prev MLP's L3) must be done
        __syncthreads();
        #pragma unroll
        for (int j = 0; j < 16; ++j)
            *reinterpret_cast<float2*>(&Hs[(uwid * 16 + j) * EB + 2 * lane]) =
                make_float2(h0[0][j], h0[1][j]);
        __syncthreads();

        // ---- layer 2: 64 -> 64, ReLU
        float h1[2][16];
        {
            const float* __restrict__ bb = b1 + uwid * 16;
            #pragma unroll
            for (int j = 0; j < 16; ++j) { const float b = bb[j]; h1[0][j] = b; h1[1][j] = b; }
            const float* __restrict__ wb = W1 + uwid * 16;
            #pragma unroll
            for (int k = 0; k < H; ++k) {
                const float2 xv = *reinterpret_cast<const float2*>(&Hs[k * EB + 2 * lane]);
                const float* __restrict__ w = wb + k * H;
                #pragma unroll
                for (int j = 0; j < 16; ++j) {
                    h1[0][j] = fmaf(xv.x, w[j], h1[0][j]);
                    h1[1][j] = fmaf(xv.y, w[j], h1[1][j]);
                }
            }
            #pragma unroll
            for (int i = 0; i < 2; ++i)
                #pragma unroll
                for (int j = 0; j < 16; ++j) h1[i][j] = fmaxf(h1[i][j], 0.0f);
        }

        __syncthreads();   // all h0 reads done before overwrite
        #pragma unroll
        for (int j = 0; j < 16; ++j)
            *reinterpret_cast<float2*>(&Hs[(uwid * 16 + j) * EB + 2 * lane]) =
                make_float2(h1[0][j], h1[1][j]);
        __syncthreads();

        // ---- layer 3: 64 -> 16. Wave w owns outs [4w, 4w+4).
        {
            float o[2][4];
            const float* __restrict__ bb = b2 + uwid * 4;
            #pragma unroll
            for (int j = 0; j < 4; ++j) { const float b = bb[j]; o[0][j] = b; o[1][j] = b; }
            const float* __restrict__ wb = W2 + uwid * 4;
            #pragma unroll
            for (int k = 0; k < H; ++k) {
                const float2 xv = *reinterpret_cast<const float2*>(&Hs[k * EB + 2 * lane]);
                const float* __restrict__ w = wb + k * D_OUT;
                #pragma unroll
                for (int j = 0; j < 4; ++j) {
                    o[0][j] = fmaf(xv.x, w[j], o[0][j]);
                    o[1][j] = fmaf(xv.y, w[j], o[1][j]);
                }
            }
            // masked scatter-add: 2 edges x 4 outs per thread
            #pragma unroll
            for (int i = 0; i < 2; ++i) {
                const int e = 2 * lane + i;
                const float m = ms[e];
                const int node = nodes[which][e];
                float* __restrict__ dst = acc_out + (size_t)node * D_OUT + uwid * 4;
                #pragma unroll
                for (int j = 0; j < 4; ++j)
                    atomicAdd(dst + j, o[i][j] * m);
            }
        }
    };

    run_mlp(fW0, fb0, fW1, fb1, fW2, fb2, 0);
    run_mlp(tW0, tb0, tW1, tb1, tW2, tb2, 1);
}

__global__ __launch_bounds__(256) void tanh_inplace(float* __restrict__ p, int n4)
{
    const int i = blockIdx.x * blockDim.x + threadIdx.x;
    if (i >= n4) return;
    float4 v = reinterpret_cast<float4*>(p)[i];
    v.x = tanhf(v.x); v.y = tanhf(v.y); v.z = tanhf(v.z); v.w = tanhf(v.w);
    reinterpret_cast<float4*>(p)[i] = v;
}

extern "C" void kernel_launch(void* const* d_in, const int* in_sizes, int n_in,
                              void* d_out, int out_size, void* d_ws, size_t ws_size,
                              hipStream_t stream)
{
    const float* coords = (const float*)d_in[0];
    const float* feat   = (const float*)d_in[1];
    const float* mask   = (const float*)d_in[2];
    const int*   a_from = (const int*)d_in[3];
    const int*   a_to   = (const int*)d_in[4];
    const float* fW0 = (const float*)d_in[5];
    const float* fb0 = (const float*)d_in[6];
    const float* fW1 = (const float*)d_in[7];
    const float* fb1 = (const float*)d_in[8];
    const float* fW2 = (const float*)d_in[9];
    const float* fb2 = (const float*)d_in[10];
    const float* tW0 = (const float*)d_in[11];
    const float* tb0 = (const float*)d_in[12];
    const float* tW1 = (const float*)d_in[13];
    const float* tb1 = (const float*)d_in[14];
    const float* tW2 = (const float*)d_in[15];
    const float* tb2 = (const float*)d_in[16];

    float* out = (float*)d_out;

    hipMemsetAsync(out, 0, (size_t)out_size * sizeof(float), stream);

    edge_mlp_v3<<<N_EDGES / EB, 256, 0, stream>>>(
        coords, feat, mask, a_from, a_to,
        fW0, fb0, fW1, fb1, fW2, fb2,
        tW0, tb0, tW1, tb1, tW2, tb2, out);

    const int n4 = out_size / 4;
    tanh_inplace<<<(n4 + 255) / 256, 256, 0, stream>>>(out, n4);
}

// Round 7
// 602.137 us; speedup vs baseline: 2.4555x; 2.4555x over previous
//
#include <hip/hip_runtime.h>
#include <math.h>

constexpr int N_EDGES = 800000;
constexpr int D_IN    = 40;   // 8 feat + 16 from + 16 to
constexpr int H       = 64;
constexpr int D_OUT   = 16;
constexpr int EB      = 128;  // edges per block (800000 % 128 == 0)
constexpr int OSP     = 130;  // Os row stride (pad 2): even (b64-aligned), 130%32=2
                              // -> scatter reads 2-way (free), writes ~4-way (tiny phase)

// v4 = v3 compute (scalar-path weights via wave-uniform indices, contiguous
// ds_read_b64 activations) + v2-style edge-major atomic epilogue restored via
// an LDS transpose (Os). Lesson from v3: scatter-add MUST be issued with 16
// consecutive lanes covering one edge's 16 contiguous outputs (one 64B line
// per touch); wave-split quarter-line atomics cost 8x HBM write traffic.
__global__ __launch_bounds__(256, 2) void edge_mlp_v4(
    const float* __restrict__ coords,
    const float* __restrict__ feat,
    const float* __restrict__ mask,
    const int*   __restrict__ a_from,
    const int*   __restrict__ a_to,
    const float* __restrict__ fW0, const float* __restrict__ fb0,
    const float* __restrict__ fW1, const float* __restrict__ fb1,
    const float* __restrict__ fW2, const float* __restrict__ fb2,
    const float* __restrict__ tW0, const float* __restrict__ tb0,
    const float* __restrict__ tW1, const float* __restrict__ tb1,
    const float* __restrict__ tW2, const float* __restrict__ tb2,
    float* __restrict__ acc_out)
{
    __shared__ float Xs[D_IN * EB];     // X^T: Xs[k][e], masked input
    __shared__ float Hs[H * EB];        // H^T
    __shared__ float Os[D_OUT * OSP];   // O^T staging for edge-major scatter
    __shared__ float ms[EB];
    __shared__ int   nodes[2][EB];

    const int tid  = threadIdx.x;
    const int lane = tid & 63;
    const int uwid = __builtin_amdgcn_readfirstlane(tid >> 6);  // 0..3, SGPR
    const int e0   = blockIdx.x * EB;

    // ---------------- staging ----------------
    if (tid < EB) {
        ms[tid]       = mask[e0 + tid];
        nodes[0][tid] = a_from[e0 + tid];
        nodes[1][tid] = a_to[e0 + tid];
    }
    {   // feat -> rows 0..7 ; thread = (edge, half)
        const int e = tid >> 1, half = tid & 1;
        const float m = mask[e0 + e];
        float4 v = reinterpret_cast<const float4*>(feat)[(size_t)(e0 + e) * 2 + half];
        const int r = half * 4;
        Xs[(r + 0) * EB + e] = v.x * m;
        Xs[(r + 1) * EB + e] = v.y * m;
        Xs[(r + 2) * EB + e] = v.z * m;
        Xs[(r + 3) * EB + e] = v.w * m;
    }
    {   // coords -> rows 8..23 (from), 24..39 (to) ; thread = (edge, which)
        const int e = tid >> 1, which = tid & 1;
        const float m = mask[e0 + e];
        const int n = which ? a_to[e0 + e] : a_from[e0 + e];
        const float4* c4 = reinterpret_cast<const float4*>(coords + (size_t)n * 16);
        const int rbase = 8 + which * 16;
        #pragma unroll
        for (int q = 0; q < 4; ++q) {
            float4 v = c4[q];
            Xs[(rbase + 4*q + 0) * EB + e] = v.x * m;
            Xs[(rbase + 4*q + 1) * EB + e] = v.y * m;
            Xs[(rbase + 4*q + 2) * EB + e] = v.z * m;
            Xs[(rbase + 4*q + 3) * EB + e] = v.w * m;
        }
    }
    __syncthreads();

    auto run_mlp = [&](const float* __restrict__ W0, const float* __restrict__ b0,
                       const float* __restrict__ W1, const float* __restrict__ b1,
                       const float* __restrict__ W2, const float* __restrict__ b2,
                       const int which)
    {
        // ---- layer 1: 40 -> 64, ReLU. acc[edge][j], j in wave's 16-chunk.
        float h0[2][16];
        {
            const float* __restrict__ bb = b0 + uwid * 16;
            #pragma unroll
            for (int j = 0; j < 16; ++j) { const float b = bb[j]; h0[0][j] = b; h0[1][j] = b; }
            const float* __restrict__ wb = W0 + uwid * 16;
            #pragma unroll
            for (int k = 0; k < D_IN; ++k) {
                const float2 xv = *reinterpret_cast<const float2*>(&Xs[k * EB + 2 * lane]);
                const float* __restrict__ w = wb + k * H;
                #pragma unroll
                for (int j = 0; j < 16; ++j) {
                    h0[0][j] = fmaf(xv.x, w[j], h0[0][j]);
                    h0[1][j] = fmaf(xv.y, w[j], h0[1][j]);
                }
            }
            #pragma unroll
            for (int i = 0; i < 2; ++i)
                #pragma unroll
                for (int j = 0; j < 16; ++j) h0[i][j] = fmaxf(h0[i][j], 0.0f);
        }

        // prior readers of Hs (prev MLP's L3) are past their barrier already
        __syncthreads();
        #pragma unroll
        for (int j = 0; j < 16; ++j)
            *reinterpret_cast<float2*>(&Hs[(uwid * 16 + j) * EB + 2 * lane]) =
                make_float2(h0[0][j], h0[1][j]);
        __syncthreads();

        // ---- layer 2: 64 -> 64, ReLU
        float h1[2][16];
        {
            const float* __restrict__ bb = b1 + uwid * 16;
            #pragma unroll
            for (int j = 0; j < 16; ++j) { const float b = bb[j]; h1[0][j] = b; h1[1][j] = b; }
            const float* __restrict__ wb = W1 + uwid * 16;
            #pragma unroll
            for (int k = 0; k < H; ++k) {
                const float2 xv = *reinterpret_cast<const float2*>(&Hs[k * EB + 2 * lane]);
                const float* __restrict__ w = wb + k * H;
                #pragma unroll
                for (int j = 0; j < 16; ++j) {
                    h1[0][j] = fmaf(xv.x, w[j], h1[0][j]);
                    h1[1][j] = fmaf(xv.y, w[j], h1[1][j]);
                }
            }
            #pragma unroll
            for (int i = 0; i < 2; ++i)
                #pragma unroll
                for (int j = 0; j < 16; ++j) h1[i][j] = fmaxf(h1[i][j], 0.0f);
        }

        __syncthreads();   // all Hs(h0) reads done before overwrite
        #pragma unroll
        for (int j = 0; j < 16; ++j)
            *reinterpret_cast<float2*>(&Hs[(uwid * 16 + j) * EB + 2 * lane]) =
                make_float2(h1[0][j], h1[1][j]);
        __syncthreads();

        // ---- layer 3: 64 -> 16. Wave w computes outs [4w, 4w+4) for its edges.
        {
            float o[2][4];
            const float* __restrict__ bb = b2 + uwid * 4;
            #pragma unroll
            for (int j = 0; j < 4; ++j) { const float b = bb[j]; o[0][j] = b; o[1][j] = b; }
            const float* __restrict__ wb = W2 + uwid * 4;
            #pragma unroll
            for (int k = 0; k < H; ++k) {
                const float2 xv = *reinterpret_cast<const float2*>(&Hs[k * EB + 2 * lane]);
                const float* __restrict__ w = wb + k * D_OUT;
                #pragma unroll
                for (int j = 0; j < 4; ++j) {
                    o[0][j] = fmaf(xv.x, w[j], o[0][j]);
                    o[1][j] = fmaf(xv.y, w[j], o[1][j]);
                }
            }

            // bake mask before staging (out * m)
            const float m0 = ms[2 * lane];
            const float m1 = ms[2 * lane + 1];
            #pragma unroll
            for (int j = 0; j < 4; ++j) { o[0][j] *= m0; o[1][j] *= m1; }

            // ---- transpose through Os so the scatter is edge-major
            __syncthreads();   // previous MLP's scatter reads of Os are done
            #pragma unroll
            for (int j = 0; j < 4; ++j)
                *reinterpret_cast<float2*>(&Os[(uwid * 4 + j) * OSP + 2 * lane]) =
                    make_float2(o[0][j], o[1][j]);
            __syncthreads();

            // ---- scatter: lanes 0..15 cover one edge's 16 contiguous outputs
            const int ox  = lane & 15;   // output index
            const int sub = lane >> 4;   // 0..3
            #pragma unroll
            for (int p = 0; p < 8; ++p) {
                const int e    = uwid * 4 + sub + 16 * p;
                const int node = nodes[which][e];
                const float v  = Os[ox * OSP + e];
                atomicAdd(acc_out + (size_t)node * D_OUT + ox, v);
            }
        }
    };

    run_mlp(fW0, fb0, fW1, fb1, fW2, fb2, 0);
    run_mlp(tW0, tb0, tW1, tb1, tW2, tb2, 1);
}

__global__ __launch_bounds__(256) void tanh_inplace(float* __restrict__ p, int n4)
{
    const int i = blockIdx.x * blockDim.x + threadIdx.x;
    if (i >= n4) return;
    float4 v = reinterpret_cast<float4*>(p)[i];
    v.x = tanhf(v.x); v.y = tanhf(v.y); v.z = tanhf(v.z); v.w = tanhf(v.w);
    reinterpret_cast<float4*>(p)[i] = v;
}

extern "C" void kernel_launch(void* const* d_in, const int* in_sizes, int n_in,
                              void* d_out, int out_size, void* d_ws, size_t ws_size,
                              hipStream_t stream)
{
    const float* coords = (const float*)d_in[0];
    const float* feat   = (const float*)d_in[1];
    const float* mask   = (const float*)d_in[2];
    const int*   a_from = (const int*)d_in[3];
    const int*   a_to   = (const int*)d_in[4];
    const float* fW0 = (const float*)d_in[5];
    const float* fb0 = (const float*)d_in[6];
    const float* fW1 = (const float*)d_in[7];
    const float* fb1 = (const float*)d_in[8];
    const float* fW2 = (const float*)d_in[9];
    const float* fb2 = (const float*)d_in[10];
    const float* tW0 = (const float*)d_in[11];
    const float* tb0 = (const float*)d_in[12];
    const float* tW1 = (const float*)d_in[13];
    const float* tb1 = (const float*)d_in[14];
    const float* tW2 = (const float*)d_in[15];
    const float* tb2 = (const float*)d_in[16];

    float* out = (float*)d_out;

    hipMemsetAsync(out, 0, (size_t)out_size * sizeof(float), stream);

    edge_mlp_v4<<<N_EDGES / EB, 256, 0, stream>>>(
        coords, feat, mask, a_from, a_to,
        fW0, fb0, fW1, fb1, fW2, fb2,
        tW0, tb0, tW1, tb1, tW2, tb2, out);

    const int n4 = out_size / 4;
    tanh_inplace<<<(n4 + 255) / 256, 256, 0, stream>>>(out, n4);
}